// Round 4
// baseline (1723.370 us; speedup 1.0000x reference)
//
#include <hip/hip_runtime.h>
#include <hip/hip_fp16.h>

#define NNODES 100000
#define NEDGES 3200000
#define F_IN   256
#define F_HID  32
#define F_OUT  16

#define NB   196      // ceil(100000/512) buckets of 512 nodes
#define NPB  512      // nodes per bucket
#define CAP  20480    // fixed capacity per bucket region (mean 16384, +32 sigma)
#define NCHUNK 256    // phase-A blocks (keeps reservations ~64 records = dense writes)
#define CHUNK  12500  // edges per phase-A block
#define NND_AL 100352 // padded node count (392*256)

#define GRID1 ((NNODES + 63) / 64)   // 1563 blocks, 64 rows/block (16/wave)
#define XT_RS 130                    // xt row stride (floats): pad 2 -> 4-way max
#define ACC_S 33                     // LDS acc row stride (bank-spread padding)

typedef _Float16 half_t;
typedef half_t half8 __attribute__((ext_vector_type(8)));
typedef float f32x4 __attribute__((ext_vector_type(4)));
typedef const __attribute__((address_space(1))) unsigned int* gas_u32;
typedef __attribute__((address_space(3))) unsigned int* las_u32;

// ---------------- CSR-free build: bucket partition only ----------------
// Lesson (r1/r3 counters): scattered 4B HBM writes cost a full 64B line each
// (k_place: 196MB WRITE for 12.8MB payload). Only block-local contiguous
// reservations write densely (r0 phaseA: 15MB). So: partition edges into
// per-bucket contiguous record regions (dense writes), and let the gather
// kernels consume records directly via LDS accumulation -- no csr, no scan.

__global__ void k_init(int* __restrict__ bcur) {
    if (threadIdx.x < NB) bcur[threadIdx.x] = threadIdx.x * CAP;
}

// Phase A: partition edges into bucket regions as packed records (src<<9)|dstLocal.
// 1024 threads/block (16 waves/CU at 256 blocks) for latency hiding; chunking
// unchanged so per-bucket reservations stay ~64 contiguous records (4 lines).
__global__ __launch_bounds__(1024) void k_phaseA(
        const int* __restrict__ src, const int* __restrict__ dst,
        int* __restrict__ bcur, unsigned int* __restrict__ rec) {
    __shared__ int lh[NB];
    __shared__ int lcur[NB];
    int t = threadIdx.x;
    int e0 = blockIdx.x * CHUNK;
    if (t < NB) lh[t] = 0;
    __syncthreads();
    for (int i = t; i < CHUNK; i += 1024)
        atomicAdd(&lh[dst[e0 + i] >> 9], 1);
    __syncthreads();
    if (t < NB) lcur[t] = lh[t] ? atomicAdd(&bcur[t], lh[t]) : 0;
    __syncthreads();
    for (int i = t; i < CHUNK; i += 1024) {
        int s = src[e0 + i], d = dst[e0 + i];
        int b = d >> 9;
        int pos = atomicAdd(&lcur[b], 1);
        rec[pos] = ((unsigned)s << 9) | (unsigned)(d & 511);
    }
}

__global__ __launch_bounds__(256) void k_zero(int* __restrict__ deg) {
    deg[blockIdx.x * 256 + threadIdx.x] = 0;
}

// degree histogram: atomics on 400KB of counters (L2-resident, ~32 edges/node)
__global__ __launch_bounds__(256) void k_deg(
        const int* __restrict__ dst, int* __restrict__ deg) {
    int stride = gridDim.x * 256;
    for (int i = blockIdx.x * 256 + threadIdx.x; i < NEDGES; i += stride)
        atomicAdd(&deg[dst[i]], 1);
}

__global__ __launch_bounds__(256) void k_dinv(
        const int* __restrict__ deg, float* __restrict__ dinv) {
    int n = blockIdx.x * 256 + threadIdx.x;
    if (n < NNODES) dinv[n] = rsqrtf((float)deg[n] + 1.0f);
}

// ---------------- layer-1 GEMM via MFMA + async LDS staging ----------------

__global__ __launch_bounds__(256) void k_gemm1(
        const float* __restrict__ x, const float* __restrict__ W1,
        const float* __restrict__ dinv, __half2* __restrict__ g1) {
    __shared__ half_t Wt[32 * 264];       // [f][k] fp16, 16.9 KB
    __shared__ float xt[4][16 * XT_RS];   // per-wave A staging, 33.3 KB
    int t = threadIdx.x;
    int wave = t >> 6, lane = t & 63;
    int m = lane & 15, q = lane >> 4;
    int row0 = blockIdx.x * 64 + wave * 16;

    for (int i = t; i < F_IN * F_HID; i += 256) {
        int k = i >> 5, f = i & 31;
        Wt[f * 264 + k] = (half_t)W1[i];
    }
    __syncthreads();

    half8 B[2][8];
    #pragma unroll
    for (int ft = 0; ft < 2; ++ft)
        #pragma unroll
        for (int kc = 0; kc < 8; ++kc)
            B[ft][kc] = *(const half8*)&Wt[(ft * 16 + m) * 264 + kc * 32 + q * 8];

    float* xw = xt[wave];
    f32x4 acc0 = {0.f, 0.f, 0.f, 0.f};
    f32x4 acc1 = {0.f, 0.f, 0.f, 0.f};
    #pragma unroll
    for (int kh = 0; kh < 2; ++kh) {
        #pragma unroll
        for (int r = 0; r < 16; ++r) {
            int grow = row0 + r; if (grow >= NNODES) grow = NNODES - 1;
            const float* gp = &x[(size_t)grow * F_IN + kh * 128 + lane];
            __builtin_amdgcn_global_load_lds((gas_u32)gp,
                (las_u32)&xw[r * XT_RS], 4, 0, 0);
            __builtin_amdgcn_global_load_lds((gas_u32)(gp + 64),
                (las_u32)&xw[r * XT_RS + 64], 4, 0, 0);
        }
        asm volatile("s_waitcnt vmcnt(0)" ::: "memory");
        #pragma unroll
        for (int kc = 0; kc < 4; ++kc) {
            const float* sp = &xw[m * XT_RS + kc * 32 + q * 8];
            float2 x0 = *(const float2*)sp;
            float2 x1 = *(const float2*)(sp + 2);
            float2 x2 = *(const float2*)(sp + 4);
            float2 x3 = *(const float2*)(sp + 6);
            half8 A;
            A[0] = (half_t)x0.x; A[1] = (half_t)x0.y;
            A[2] = (half_t)x1.x; A[3] = (half_t)x1.y;
            A[4] = (half_t)x2.x; A[5] = (half_t)x2.y;
            A[6] = (half_t)x3.x; A[7] = (half_t)x3.y;
            acc0 = __builtin_amdgcn_mfma_f32_16x16x32_f16(A, B[0][kh * 4 + kc], acc0, 0, 0, 0);
            acc1 = __builtin_amdgcn_mfma_f32_16x16x32_f16(A, B[1][kh * 4 + kc], acc1, 0, 0, 0);
        }
        if (kh == 0) asm volatile("s_waitcnt lgkmcnt(0)" ::: "memory");
    }

    // epilogue: dinv scale -> repack via xt (stride 33) -> coalesced half2 stores
    __syncthreads();
    float* sb = xw;
    #pragma unroll
    for (int r = 0; r < 4; ++r) {
        int rl = q * 4 + r;
        int grow = row0 + rl; if (grow >= NNODES) grow = NNODES - 1;
        float dv = dinv[grow];
        sb[rl * 33 + m]      = acc0[r] * dv;
        sb[rl * 33 + 16 + m] = acc1[r] * dv;
    }
    __syncthreads();
    int rl = (t >> 2) & 15;
    int w2 = t >> 6;
    int c0 = (t & 3) * 8;
    int grow = blockIdx.x * 64 + w2 * 16 + rl;
    if (grow < NNODES) {
        const float* sp = &xt[w2][rl * 33 + c0];
        __half2 h0 = __floats2half2_rn(sp[0], sp[1]);
        __half2 h1 = __floats2half2_rn(sp[2], sp[3]);
        __half2 h2 = __floats2half2_rn(sp[4], sp[5]);
        __half2 h3 = __floats2half2_rn(sp[6], sp[7]);
        __half2* gp = &g1[(size_t)grow * 16 + (c0 >> 1)];
        gp[0] = h0; gp[1] = h1; gp[2] = h2; gp[3] = h3;
    }
}

// ---------------- bucket gather 1: LDS-accumulate + relu + [Wm|Wv] ----------------
// One 1024-thread block per 512-node bucket. Streams the bucket's contiguous
// rec region; 16 threads/edge each ds_add_f32 two channels of the gathered
// g1 row (L2-resident 6.4MB table) into acc[512][33] (67.6KB LDS, stride-33
// spreads banks). Epilogue fuses self-loop, dinv, bias, relu, and the second
// transform -- the per-node CSR and its scatter writes are gone entirely.

__global__ __launch_bounds__(1024) void k_bg1(
        const unsigned int* __restrict__ rec, const int* __restrict__ bcur,
        const float* __restrict__ dinv, const __half2* __restrict__ g1,
        const float* __restrict__ b1, const float* __restrict__ Wm,
        const float* __restrict__ Wv, __half2* __restrict__ g2) {
    __shared__ float acc[NPB * ACC_S];    // 67.6 KB
    __shared__ float Wcat[F_HID * 32];    // 4 KB
    int t = threadIdx.x, b = blockIdx.x;
    for (int i = t; i < NPB * ACC_S; i += 1024) acc[i] = 0.f;
    if (t < F_HID * 32) {
        int k = t >> 5, j = t & 31;
        Wcat[t] = (j < F_OUT) ? Wm[k * F_OUT + j] : Wv[k * F_OUT + (j - F_OUT)];
    }
    __syncthreads();

    int lo = b * CAP, hi = bcur[b];
    int f2 = t & 15, grp = t >> 4;
    for (int e = lo + grp; e < hi; e += 64) {
        unsigned r = rec[e];
        int s = r >> 9, dl = r & 511;
        float2 v = __half22float2(g1[(size_t)s * 16 + f2]);
        atomicAdd(&acc[dl * ACC_S + 2 * f2],     v.x);
        atomicAdd(&acc[dl * ACC_S + 2 * f2 + 1], v.y);
    }
    __syncthreads();

    // phase 1: h = relu(dinv*(acc + self) + b1)  (written back into acc)
    int ng = t >> 4;
    float bx = b1[2 * f2], by = b1[2 * f2 + 1];
    float dv[8];
    #pragma unroll
    for (int p = 0; p < 8; ++p) {
        int n = ng + 64 * p;
        int g = b * NPB + n;
        if (g < NNODES) {
            dv[p] = dinv[g];
            float2 sf = __half22float2(g1[(size_t)g * 16 + f2]);
            float h0 = dv[p] * (acc[n * ACC_S + 2 * f2]     + sf.x) + bx;
            float h1 = dv[p] * (acc[n * ACC_S + 2 * f2 + 1] + sf.y) + by;
            acc[n * ACC_S + 2 * f2]     = h0 > 0.f ? h0 : 0.f;
            acc[n * ACC_S + 2 * f2 + 1] = h1 > 0.f ? h1 : 0.f;
        }
    }
    __syncthreads();

    // phase 2: g2 = (h @ [Wm|Wv]) * dinv
    #pragma unroll
    for (int p = 0; p < 8; ++p) {
        int n = ng + 64 * p;
        int g = b * NPB + n;
        if (g < NNODES) {
            float o0 = 0.f, o1 = 0.f;
            #pragma unroll
            for (int k = 0; k < F_HID; ++k) {
                float hv = acc[n * ACC_S + k];
                o0 = fmaf(hv, Wcat[k * 32 + 2 * f2], o0);
                o1 = fmaf(hv, Wcat[k * 32 + 2 * f2 + 1], o1);
            }
            g2[(size_t)g * 16 + f2] = __floats2half2_rn(o0 * dv[p], o1 * dv[p]);
        }
    }
}

// ---------------- bucket gather 2: LDS-accumulate + bias + mu/sigma split ------

__global__ __launch_bounds__(1024) void k_bg2(
        const unsigned int* __restrict__ rec, const int* __restrict__ bcur,
        const float* __restrict__ dinv, const __half2* __restrict__ g2,
        const float* __restrict__ bm, const float* __restrict__ bv,
        float* __restrict__ out) {
    __shared__ float acc[NPB * ACC_S];    // 67.6 KB
    int t = threadIdx.x, b = blockIdx.x;
    for (int i = t; i < NPB * ACC_S; i += 1024) acc[i] = 0.f;
    __syncthreads();

    int lo = b * CAP, hi = bcur[b];
    int f2 = t & 15, grp = t >> 4;
    for (int e = lo + grp; e < hi; e += 64) {
        unsigned r = rec[e];
        int s = r >> 9, dl = r & 511;
        float2 v = __half22float2(g2[(size_t)s * 16 + f2]);
        atomicAdd(&acc[dl * ACC_S + 2 * f2],     v.x);
        atomicAdd(&acc[dl * ACC_S + 2 * f2 + 1], v.y);
    }
    __syncthreads();

    int c = 2 * f2;   // c even: c and c+1 always on the same mu/sigma side
    float c0b = (c < F_OUT) ? bm[c] : bv[c - F_OUT];
    float c1b = (c < F_OUT) ? bm[c + 1] : bv[c + 1 - F_OUT];
    int ng = t >> 4;
    #pragma unroll
    for (int p = 0; p < 8; ++p) {
        int n = ng + 64 * p;
        int g = b * NPB + n;
        if (g < NNODES) {
            float dvv = dinv[g];
            float2 sf = __half22float2(g2[(size_t)g * 16 + f2]);
            float o0 = dvv * (acc[n * ACC_S + c]     + sf.x) + c0b;
            float o1 = dvv * (acc[n * ACC_S + c + 1] + sf.y) + c1b;
            float* dp = (c < F_OUT)
                ? &out[(size_t)g * F_OUT + c]
                : &out[(size_t)NNODES * F_OUT + (size_t)g * F_OUT + (c - F_OUT)];
            float2 o = { o0, o1 };
            *(float2*)dp = o;
        }
    }
}

// ---------------- launch ----------------

extern "C" void kernel_launch(void* const* d_in, const int* in_sizes, int n_in,
                              void* d_out, int out_size, void* d_ws, size_t ws_size,
                              hipStream_t stream) {
    const float* x   = (const float*)d_in[0];
    const int*   ei  = (const int*)  d_in[1];
    const float* W1  = (const float*)d_in[2];
    const float* b1  = (const float*)d_in[3];
    const float* Wm  = (const float*)d_in[4];
    const float* bm  = (const float*)d_in[5];
    const float* Wv  = (const float*)d_in[6];
    const float* bv  = (const float*)d_in[7];
    float* out = (float*)d_out;

    const int* src = ei;
    const int* dst = ei + NEDGES;

    // workspace layout (bytes), ~30 MB:
    char* ws = (char*)d_ws;
    float*        dinv = (float*)ws;        ws += NND_AL * 4;
    int*          deg  = (int*)ws;          ws += NND_AL * 4;
    int*          bcur = (int*)ws;          ws += 256 * 4;
    unsigned int* rec  = (unsigned int*)ws; ws += (size_t)NB * CAP * 4;   // 16.06 MB
    __half2*      g1   = (__half2*)ws;      ws += (size_t)NND_AL * 16 * 4; // 6.42 MB
    __half2*      g2   = (__half2*)ws;

    // build: bucket partition + degree
    k_init  <<<1, 256, 0, stream>>>(bcur);
    k_zero  <<<NND_AL / 256, 256, 0, stream>>>(deg);
    k_phaseA<<<NCHUNK, 1024, 0, stream>>>(src, dst, bcur, rec);
    k_deg   <<<2048, 256, 0, stream>>>(dst, deg);
    k_dinv  <<<NND_AL / 256, 256, 0, stream>>>(deg, dinv);

    // layer 1 GEMM (MFMA, async LDS staging)
    k_gemm1<<<GRID1, 256, 0, stream>>>(x, W1, dinv, g1);

    // bucket gather 1 (+ relu + [Wm|Wv] transform)
    k_bg1<<<NB, 1024, 0, stream>>>(rec, bcur, dinv, g1, b1, Wm, Wv, g2);

    // bucket gather 2 (+ bias + mu/sigma split)
    k_bg2<<<NB, 1024, 0, stream>>>(rec, bcur, dinv, g2, bm, bv, out);
}

// Round 5
// 344.313 us; speedup vs baseline: 5.0052x; 5.0052x over previous
//
#include <hip/hip_runtime.h>
#include <hip/hip_fp16.h>

#define NNODES 100000
#define NEDGES 3200000
#define F_IN   256
#define F_HID  32
#define F_OUT  16

#define NB   196      // ceil(100000/512) buckets of 512 nodes
#define NPB  512      // nodes per bucket
#define CAP  20480    // fixed capacity per bucket region (mean 16327, +32 sigma)
#define NCHUNK 256    // phase-A blocks: keeps reservations ~64 records = dense writes
#define CHUNK  12500  // edges per phase-A block

#define GRID1 ((NNODES + 63) / 64)   // 1563 blocks, 64 rows/block (16/wave)
#define XT_RS 130                    // xt row stride (floats): pad 2 -> 4-way max

typedef _Float16 half_t;
typedef half_t half8 __attribute__((ext_vector_type(8)));
typedef float f32x4 __attribute__((ext_vector_type(4)));
typedef const __attribute__((address_space(1))) unsigned int* gas_u32;
typedef __attribute__((address_space(3))) unsigned int* las_u32;

// ---------------- CSR build (fixed-capacity buckets) ----------------
// Verified lessons (r1/r3/r4 counters):
//  - scattered 4B HBM writes cost a full 64B line each (r3 k_place: 196MB
//    WRITE for a 12.8MB payload) -> only block-local contiguous reservations
//    write densely (this scheme: ~15MB).
//  - finer reservations (r1: 1024 blocks) fragment lines -> 4x write amp.
//    So NCHUNK stays 256; occupancy comes from 1024 threads/block instead.
//  - gather-side kernels must run thousands of blocks; 196-block LDS
//    accumulation (r4) starves the GPU and thrashes per-XCD 4MB L2.

__global__ void k_init(int* __restrict__ bcur) {
    if (threadIdx.x < NB) bcur[threadIdx.x] = threadIdx.x * CAP;
}

// Phase A: partition edges into bucket regions as packed records (src<<9)|dstLocal.
// 1024 threads/block (16 waves/CU) for latency hiding; chunking unchanged so
// per-bucket reservations stay ~64 contiguous records (4 full lines, dense).
__global__ __launch_bounds__(1024) void k_phaseA(
        const int* __restrict__ src, const int* __restrict__ dst,
        int* __restrict__ bcur, unsigned int* __restrict__ rec) {
    __shared__ int lh[NB];
    __shared__ int lcur[NB];
    int t = threadIdx.x;
    int e0 = blockIdx.x * CHUNK;
    if (t < NB) lh[t] = 0;
    __syncthreads();
    for (int i = t; i < CHUNK; i += 1024)
        atomicAdd(&lh[dst[e0 + i] >> 9], 1);
    __syncthreads();
    if (t < NB) lcur[t] = lh[t] ? atomicAdd(&bcur[t], lh[t]) : 0;
    __syncthreads();
    for (int i = t; i < CHUNK; i += 1024) {
        int s = src[e0 + i], d = dst[e0 + i];
        int b = d >> 9;
        int pos = atomicAdd(&lcur[b], 1);
        rec[pos] = ((unsigned)s << 9) | (unsigned)(d & 511);
    }
}

// Phase B: one block (1024 thr, 16 waves) per bucket: hist -> shuffle scan ->
// rowptr/cnt/dinv, then place srcs into the bucket's csr region.
__global__ __launch_bounds__(1024) void k_phaseB(
        const unsigned int* __restrict__ rec, const int* __restrict__ bcur,
        int* __restrict__ rowptr, int* __restrict__ cnt,
        float* __restrict__ dinv, int* __restrict__ csr) {
    __shared__ int lh[NPB];
    __shared__ int lsc[NPB];
    __shared__ int wsum[16];
    int t = threadIdx.x, b = blockIdx.x;
    int lo = b * CAP, hi = bcur[b];
    if (t < NPB) lh[t] = 0;
    __syncthreads();
    for (int i = lo + t; i < hi; i += 1024)
        atomicAdd(&lh[rec[i] & 511], 1);
    __syncthreads();
    int lane = t & 63, w = t >> 6;
    int my = (t < NPB) ? lh[t] : 0;
    int v = my;
    #pragma unroll
    for (int d = 1; d < 64; d <<= 1) {
        int tmp = __shfl_up(v, d, 64);
        if (lane >= d) v += tmp;
    }
    if (lane == 63) wsum[w] = v;
    __syncthreads();
    if (w == 0) {
        int s = (lane < 16) ? wsum[lane] : 0;
        #pragma unroll
        for (int d = 1; d < 16; d <<= 1) {
            int tmp = __shfl_up(s, d, 64);
            if (lane >= d) s += tmp;
        }
        if (lane < 16) wsum[lane] = s;
    }
    __syncthreads();
    int ex = v + (w > 0 ? wsum[w - 1] : 0) - my;   // exclusive
    int node = b * NPB + t;
    if (t < NPB) {
        lsc[t] = ex;
        if (node < NNODES) {
            rowptr[node] = lo + ex;
            cnt[node] = my;
            dinv[node] = rsqrtf((float)my + 1.0f);
        }
    }
    __syncthreads();
    for (int i = lo + t; i < hi; i += 1024) {
        unsigned r = rec[i];
        int dl = r & 511;
        int p = atomicAdd(&lsc[dl], 1);
        csr[lo + p] = (int)(r >> 9);
    }
}

// ---------------- layer-1 GEMM via MFMA + async LDS staging ----------------
// Wt: W1 transposed to fp16 in LDS once -> B frags via 16 ds_read_b128 (one-time).
// A: per-wave 16x128 fp32 tile staged with global_load_lds (coalesced 256B chunks),
// stride-130 rows; fragments read as 4x float2 (8B aligned, ~4-way max conflict).
// No block barriers in the K-loop; epilogue reuses xt as repack buffer.

__global__ __launch_bounds__(256) void k_gemm1(
        const float* __restrict__ x, const float* __restrict__ W1,
        const float* __restrict__ dinv, __half2* __restrict__ g1) {
    __shared__ half_t Wt[32 * 264];       // [f][k] fp16, 16.9 KB
    __shared__ float xt[4][16 * XT_RS];   // per-wave A staging, 33.3 KB
    int t = threadIdx.x;
    int wave = t >> 6, lane = t & 63;
    int m = lane & 15, q = lane >> 4;
    int row0 = blockIdx.x * 64 + wave * 16;

    for (int i = t; i < F_IN * F_HID; i += 256) {
        int k = i >> 5, f = i & 31;
        Wt[f * 264 + k] = (half_t)W1[i];
    }
    __syncthreads();

    half8 B[2][8];
    #pragma unroll
    for (int ft = 0; ft < 2; ++ft)
        #pragma unroll
        for (int kc = 0; kc < 8; ++kc)
            B[ft][kc] = *(const half8*)&Wt[(ft * 16 + m) * 264 + kc * 32 + q * 8];

    float* xw = xt[wave];
    f32x4 acc0 = {0.f, 0.f, 0.f, 0.f};
    f32x4 acc1 = {0.f, 0.f, 0.f, 0.f};
    #pragma unroll
    for (int kh = 0; kh < 2; ++kh) {
        #pragma unroll
        for (int r = 0; r < 16; ++r) {
            int grow = row0 + r; if (grow >= NNODES) grow = NNODES - 1;
            const float* gp = &x[(size_t)grow * F_IN + kh * 128 + lane];
            __builtin_amdgcn_global_load_lds((gas_u32)gp,
                (las_u32)&xw[r * XT_RS], 4, 0, 0);
            __builtin_amdgcn_global_load_lds((gas_u32)(gp + 64),
                (las_u32)&xw[r * XT_RS + 64], 4, 0, 0);
        }
        asm volatile("s_waitcnt vmcnt(0)" ::: "memory");
        #pragma unroll
        for (int kc = 0; kc < 4; ++kc) {
            const float* sp = &xw[m * XT_RS + kc * 32 + q * 8];
            float2 x0 = *(const float2*)sp;
            float2 x1 = *(const float2*)(sp + 2);
            float2 x2 = *(const float2*)(sp + 4);
            float2 x3 = *(const float2*)(sp + 6);
            half8 A;
            A[0] = (half_t)x0.x; A[1] = (half_t)x0.y;
            A[2] = (half_t)x1.x; A[3] = (half_t)x1.y;
            A[4] = (half_t)x2.x; A[5] = (half_t)x2.y;
            A[6] = (half_t)x3.x; A[7] = (half_t)x3.y;
            acc0 = __builtin_amdgcn_mfma_f32_16x16x32_f16(A, B[0][kh * 4 + kc], acc0, 0, 0, 0);
            acc1 = __builtin_amdgcn_mfma_f32_16x16x32_f16(A, B[1][kh * 4 + kc], acc1, 0, 0, 0);
        }
        if (kh == 0) asm volatile("s_waitcnt lgkmcnt(0)" ::: "memory");
    }

    // epilogue: dinv scale -> repack via xt (stride 33) -> coalesced half2 stores
    __syncthreads();
    float* sb = xw;
    #pragma unroll
    for (int r = 0; r < 4; ++r) {
        int rl = q * 4 + r;
        int grow = row0 + rl; if (grow >= NNODES) grow = NNODES - 1;
        float dv = dinv[grow];
        sb[rl * 33 + m]      = acc0[r] * dv;
        sb[rl * 33 + 16 + m] = acc1[r] * dv;
    }
    __syncthreads();
    int rl = (t >> 2) & 15;
    int w2 = t >> 6;
    int c0 = (t & 3) * 8;
    int grow = blockIdx.x * 64 + w2 * 16 + rl;
    if (grow < NNODES) {
        const float* sp = &xt[w2][rl * 33 + c0];
        __half2 h0 = __floats2half2_rn(sp[0], sp[1]);
        __half2 h1 = __floats2half2_rn(sp[2], sp[3]);
        __half2 h2 = __floats2half2_rn(sp[4], sp[5]);
        __half2 h3 = __floats2half2_rn(sp[6], sp[7]);
        __half2* gp = &g1[(size_t)grow * 16 + (c0 >> 1)];
        gp[0] = h0; gp[1] = h1; gp[2] = h2; gp[3] = h3;
    }
}

// ---------------- gather layer 1 (fp16 rows; fused relu + [Wm|Wv]) ----------------

__global__ __launch_bounds__(256) void k_gather_l1(
        const int* __restrict__ rowptr, const int* __restrict__ cnt,
        const int* __restrict__ csr,
        const float* __restrict__ dinv, const __half2* __restrict__ g,
        const float* __restrict__ b1, const float* __restrict__ Wm,
        const float* __restrict__ Wv, __half2* __restrict__ g2) {
    __shared__ float Wcat[F_HID * 32];
    __shared__ float hrow[16][F_HID + 2];
    int tx = threadIdx.x;
    for (int idx = tx; idx < F_HID * 32; idx += 256) {
        int k = idx >> 5, j = idx & 31;
        Wcat[idx] = (j < F_OUT) ? Wm[k * F_OUT + j] : Wv[k * F_OUT + (j - F_OUT)];
    }
    int f2 = tx & 15;
    int lr = tx >> 4;
    int node = blockIdx.x * 16 + lr;
    int start = rowptr[node], end = start + cnt[node];
    float2 acc = __half22float2(g[(size_t)node * 16 + f2]);   // self loop
    int j = start;
    for (; j + 4 <= end; j += 4) {
        int s0 = csr[j], s1 = csr[j + 1], s2 = csr[j + 2], s3 = csr[j + 3];
        float2 a0 = __half22float2(g[(size_t)s0 * 16 + f2]);
        float2 a1 = __half22float2(g[(size_t)s1 * 16 + f2]);
        float2 a2 = __half22float2(g[(size_t)s2 * 16 + f2]);
        float2 a3 = __half22float2(g[(size_t)s3 * 16 + f2]);
        acc.x += (a0.x + a1.x) + (a2.x + a3.x);
        acc.y += (a0.y + a1.y) + (a2.y + a3.y);
    }
    for (; j < end; ++j) {
        float2 a = __half22float2(g[(size_t)csr[j] * 16 + f2]);
        acc.x += a.x; acc.y += a.y;
    }
    float dv = dinv[node];
    float h0 = dv * acc.x + b1[2 * f2];
    float h1 = dv * acc.y + b1[2 * f2 + 1];
    hrow[lr][2 * f2]     = h0 > 0.f ? h0 : 0.f;
    hrow[lr][2 * f2 + 1] = h1 > 0.f ? h1 : 0.f;
    __syncthreads();
    float o0 = 0.f, o1 = 0.f;
    #pragma unroll
    for (int k = 0; k < F_HID; ++k) {
        float hv = hrow[lr][k];
        o0 = fmaf(hv, Wcat[k * 32 + 2 * f2], o0);
        o1 = fmaf(hv, Wcat[k * 32 + 2 * f2 + 1], o1);
    }
    g2[(size_t)node * 16 + f2] = __floats2half2_rn(o0 * dv, o1 * dv);
}

// ---------------- gather layer 2 (fp16 rows; fused bias + mu/sigma split) --------

__global__ __launch_bounds__(256) void k_gather_out(
        const int* __restrict__ rowptr, const int* __restrict__ cnt,
        const int* __restrict__ csr,
        const float* __restrict__ dinv, const __half2* __restrict__ g,
        const float* __restrict__ bm, const float* __restrict__ bv,
        float* __restrict__ out) {
    int tx = threadIdx.x;
    int f2 = tx & 15;
    int node = blockIdx.x * 16 + (tx >> 4);
    int start = rowptr[node], end = start + cnt[node];
    float2 acc = __half22float2(g[(size_t)node * 16 + f2]);   // self loop
    int j = start;
    for (; j + 4 <= end; j += 4) {
        int s0 = csr[j], s1 = csr[j + 1], s2 = csr[j + 2], s3 = csr[j + 3];
        float2 a0 = __half22float2(g[(size_t)s0 * 16 + f2]);
        float2 a1 = __half22float2(g[(size_t)s1 * 16 + f2]);
        float2 a2 = __half22float2(g[(size_t)s2 * 16 + f2]);
        float2 a3 = __half22float2(g[(size_t)s3 * 16 + f2]);
        acc.x += (a0.x + a1.x) + (a2.x + a3.x);
        acc.y += (a0.y + a1.y) + (a2.y + a3.y);
    }
    for (; j < end; ++j) {
        float2 a = __half22float2(g[(size_t)csr[j] * 16 + f2]);
        acc.x += a.x; acc.y += a.y;
    }
    float dv = dinv[node];
    int f = 2 * f2;
    if (f < F_OUT) {
        float2 o = { dv * acc.x + bm[f], dv * acc.y + bm[f + 1] };
        *(float2*)&out[(size_t)node * F_OUT + f] = o;
    } else {
        float2 o = { dv * acc.x + bv[f - F_OUT], dv * acc.y + bv[f - F_OUT + 1] };
        *(float2*)&out[(size_t)NNODES * F_OUT + (size_t)node * F_OUT + (f - F_OUT)] = o;
    }
}

// ---------------- launch ----------------

extern "C" void kernel_launch(void* const* d_in, const int* in_sizes, int n_in,
                              void* d_out, int out_size, void* d_ws, size_t ws_size,
                              hipStream_t stream) {
    const float* x   = (const float*)d_in[0];
    const int*   ei  = (const int*)  d_in[1];
    const float* W1  = (const float*)d_in[2];
    const float* b1  = (const float*)d_in[3];
    const float* Wm  = (const float*)d_in[4];
    const float* bm  = (const float*)d_in[5];
    const float* Wv  = (const float*)d_in[6];
    const float* bv  = (const float*)d_in[7];
    float* out = (float*)d_out;

    const int* src = ei;
    const int* dst = ei + NEDGES;

    // workspace layout (4B units), ~40 MB:
    char* ws = (char*)d_ws;
    float*        dinv   = (float*)ws;        ws += 100352 * 4;
    int*          bcur   = (int*)ws;          ws += 256 * 4;
    int*          rowptr = (int*)ws;          ws += 100352 * 4;
    int*          cnt    = (int*)ws;          ws += 100352 * 4;
    int*          csr    = (int*)ws;          ws += (size_t)NB * CAP * 4;
    unsigned int* rec    = (unsigned int*)ws; ws += (size_t)NB * CAP * 4;
    __half2*      g2     = (__half2*)ws;

    __half2* g1 = (__half2*)rec;   // rec dead after k_phaseB

    // CSR build
    k_init  <<<1, 256, 0, stream>>>(bcur);
    k_phaseA<<<NCHUNK, 1024, 0, stream>>>(src, dst, bcur, rec);
    k_phaseB<<<NB, 1024, 0, stream>>>(rec, bcur, rowptr, cnt, dinv, csr);

    // layer 1 GEMM (MFMA, async LDS staging)
    k_gemm1<<<GRID1, 256, 0, stream>>>(x, W1, dinv, g1);

    // gather 1 + relu + second transform (mu|sigma fused)
    k_gather_l1<<<NNODES / 16, 256, 0, stream>>>(rowptr, cnt, csr, dinv, g1, b1, Wm, Wv, g2);

    // gather 2 + bias + split to out
    k_gather_out<<<NNODES / 16, 256, 0, stream>>>(rowptr, cnt, csr, dinv, g2, bm, bv, out);
}

// Round 6
// 337.480 us; speedup vs baseline: 5.1066x; 1.0202x over previous
//
#include <hip/hip_runtime.h>
#include <hip/hip_fp16.h>

#define NNODES 100000
#define NEDGES 3200000
#define F_IN   256
#define F_HID  32
#define F_OUT  16

#define NB   196      // ceil(100000/512) buckets of 512 nodes
#define NPB  512      // nodes per bucket
#define CAP  20480    // fixed capacity per bucket region (mean 16327, +32 sigma); = 20*1024
#define NCHUNK 256    // phase-A blocks: keeps reservations ~64 records = dense writes
#define CHUNK  12500  // edges per phase-A block
#define RPT_B  20     // phaseB records/thread (CAP/1024)
#define RPT_A  13     // phaseA dst regs/thread (ceil(CHUNK/1024))

#define GRID1 ((NNODES + 63) / 64)   // 1563 blocks, 64 rows/block (16/wave)
#define XT_RS 130                    // xt row stride (floats): pad 2 -> 4-way max

typedef _Float16 half_t;
typedef half_t half8 __attribute__((ext_vector_type(8)));
typedef float f32x4 __attribute__((ext_vector_type(4)));
typedef const __attribute__((address_space(1))) unsigned int* gas_u32;
typedef __attribute__((address_space(3))) unsigned int* las_u32;

// ---------------- CSR build (fixed-capacity buckets) ----------------
// Verified lessons (r1/r3/r4 counters):
//  - scattered 4B HBM writes cost a full 64B line each (r3 k_place: 196MB
//    WRITE for a 12.8MB payload) -> only block-local contiguous reservations
//    write densely (this scheme: ~15MB).
//  - finer reservations (r1: 1024 blocks) fragment lines -> 4x write amp.
//    So NCHUNK stays 256; occupancy comes from 1024 threads/block.
//  - gather-side kernels must run thousands of blocks; 196-block LDS
//    accumulation (r4) starves the GPU and thrashes per-XCD 4MB L2.

__global__ void k_init(int* __restrict__ bcur) {
    if (threadIdx.x < NB) bcur[threadIdx.x] = threadIdx.x * CAP;
}

// Phase A: partition edges into bucket regions as packed records (src<<9)|dstLocal.
// dst chunk is register-cached across the hist and placement passes (13 VGPRs,
// fully unrolled -> no scratch) so dst is read from memory exactly once.
__global__ __launch_bounds__(1024) void k_phaseA(
        const int* __restrict__ src, const int* __restrict__ dst,
        int* __restrict__ bcur, unsigned int* __restrict__ rec) {
    __shared__ int lh[NB];
    __shared__ int lcur[NB];
    int t = threadIdx.x;
    int e0 = blockIdx.x * CHUNK;
    if (t < NB) lh[t] = 0;

    int dcache[RPT_A];
    #pragma unroll
    for (int k = 0; k < RPT_A; ++k) {
        int i = t + k * 1024;
        dcache[k] = (i < CHUNK) ? dst[e0 + i] : -1;
    }
    __syncthreads();
    #pragma unroll
    for (int k = 0; k < RPT_A; ++k)
        if (dcache[k] >= 0) atomicAdd(&lh[dcache[k] >> 9], 1);
    __syncthreads();
    if (t < NB) lcur[t] = lh[t] ? atomicAdd(&bcur[t], lh[t]) : 0;
    __syncthreads();
    #pragma unroll
    for (int k = 0; k < RPT_A; ++k) {
        int i = t + k * 1024;
        if (dcache[k] >= 0) {
            int s = src[e0 + i];
            int d = dcache[k];
            int b = d >> 9;
            int pos = atomicAdd(&lcur[b], 1);
            rec[pos] = ((unsigned)s << 9) | (unsigned)(d & 511);
        }
    }
}

// Phase B (single-pass): load the bucket's records into registers (20/thread,
// coalesced stream, fully unrolled), then hist -> shuffle scan -> rowptr/cnt/
// dinv -> placement, all from registers. rec is read from memory exactly once.
__global__ __launch_bounds__(1024) void k_phaseB(
        const unsigned int* __restrict__ rec, const int* __restrict__ bcur,
        int* __restrict__ rowptr, int* __restrict__ cnt,
        float* __restrict__ dinv, int* __restrict__ csr) {
    __shared__ int lh[NPB];
    __shared__ int lsc[NPB];
    __shared__ int wsum[16];
    int t = threadIdx.x, b = blockIdx.x;
    int lo = b * CAP;
    int nrec = bcur[b] - lo;
    if (t < NPB) lh[t] = 0;

    unsigned rcache[RPT_B];
    #pragma unroll
    for (int k = 0; k < RPT_B; ++k) {
        int i = t + k * 1024;
        rcache[k] = (i < nrec) ? rec[lo + i] : 0xFFFFFFFFu;  // recs < 2^26: safe sentinel
    }
    __syncthreads();
    #pragma unroll
    for (int k = 0; k < RPT_B; ++k)
        if (rcache[k] != 0xFFFFFFFFu) atomicAdd(&lh[rcache[k] & 511], 1);
    __syncthreads();

    int lane = t & 63, w = t >> 6;
    int my = (t < NPB) ? lh[t] : 0;
    int v = my;
    #pragma unroll
    for (int d = 1; d < 64; d <<= 1) {
        int tmp = __shfl_up(v, d, 64);
        if (lane >= d) v += tmp;
    }
    if (lane == 63) wsum[w] = v;
    __syncthreads();
    if (w == 0) {
        int s = (lane < 16) ? wsum[lane] : 0;
        #pragma unroll
        for (int d = 1; d < 16; d <<= 1) {
            int tmp = __shfl_up(s, d, 64);
            if (lane >= d) s += tmp;
        }
        if (lane < 16) wsum[lane] = s;
    }
    __syncthreads();
    int ex = v + (w > 0 ? wsum[w - 1] : 0) - my;   // exclusive
    int node = b * NPB + t;
    if (t < NPB) {
        lsc[t] = ex;
        if (node < NNODES) {
            rowptr[node] = lo + ex;
            cnt[node] = my;
            dinv[node] = rsqrtf((float)my + 1.0f);
        }
    }
    __syncthreads();
    #pragma unroll
    for (int k = 0; k < RPT_B; ++k)
        if (rcache[k] != 0xFFFFFFFFu) {
            int dl = rcache[k] & 511;
            int p = atomicAdd(&lsc[dl], 1);
            csr[lo + p] = (int)(rcache[k] >> 9);
        }
}

// ---------------- layer-1 GEMM via MFMA + async LDS staging ----------------
// Wt: W1 transposed to fp16 in LDS once -> B frags via 16 ds_read_b128 (one-time).
// A: per-wave 16x128 fp32 tile staged with global_load_lds (coalesced 256B chunks).
// Split-wait: issue first-half-column loads (16), then second-half (16);
// vmcnt(16) -> compute kc=0,1 while second half is in flight; vmcnt(0) -> kc=2,3.

__global__ __launch_bounds__(256) void k_gemm1(
        const float* __restrict__ x, const float* __restrict__ W1,
        const float* __restrict__ dinv, __half2* __restrict__ g1) {
    __shared__ half_t Wt[32 * 264];       // [f][k] fp16, 16.9 KB
    __shared__ float xt[4][16 * XT_RS];   // per-wave A staging, 33.3 KB
    int t = threadIdx.x;
    int wave = t >> 6, lane = t & 63;
    int m = lane & 15, q = lane >> 4;
    int row0 = blockIdx.x * 64 + wave * 16;

    for (int i = t; i < F_IN * F_HID; i += 256) {
        int k = i >> 5, f = i & 31;
        Wt[f * 264 + k] = (half_t)W1[i];
    }
    __syncthreads();

    half8 B[2][8];
    #pragma unroll
    for (int ft = 0; ft < 2; ++ft)
        #pragma unroll
        for (int kc = 0; kc < 8; ++kc)
            B[ft][kc] = *(const half8*)&Wt[(ft * 16 + m) * 264 + kc * 32 + q * 8];

    float* xw = xt[wave];
    f32x4 acc0 = {0.f, 0.f, 0.f, 0.f};
    f32x4 acc1 = {0.f, 0.f, 0.f, 0.f};
    #pragma unroll
    for (int kh = 0; kh < 2; ++kh) {
        #pragma unroll
        for (int r = 0; r < 16; ++r) {       // cols [0,64): first 16 loads
            int grow = row0 + r; if (grow >= NNODES) grow = NNODES - 1;
            const float* gp = &x[(size_t)grow * F_IN + kh * 128 + lane];
            __builtin_amdgcn_global_load_lds((gas_u32)gp,
                (las_u32)&xw[r * XT_RS], 4, 0, 0);
        }
        #pragma unroll
        for (int r = 0; r < 16; ++r) {       // cols [64,128): second 16 loads
            int grow = row0 + r; if (grow >= NNODES) grow = NNODES - 1;
            const float* gp = &x[(size_t)grow * F_IN + kh * 128 + lane];
            __builtin_amdgcn_global_load_lds((gas_u32)(gp + 64),
                (las_u32)&xw[r * XT_RS + 64], 4, 0, 0);
        }
        #pragma unroll
        for (int kc = 0; kc < 4; ++kc) {
            if (kc == 0) asm volatile("s_waitcnt vmcnt(16)" ::: "memory");
            if (kc == 2) asm volatile("s_waitcnt vmcnt(0)" ::: "memory");
            const float* sp = &xw[m * XT_RS + kc * 32 + q * 8];
            float2 x0 = *(const float2*)sp;
            float2 x1 = *(const float2*)(sp + 2);
            float2 x2 = *(const float2*)(sp + 4);
            float2 x3 = *(const float2*)(sp + 6);
            half8 A;
            A[0] = (half_t)x0.x; A[1] = (half_t)x0.y;
            A[2] = (half_t)x1.x; A[3] = (half_t)x1.y;
            A[4] = (half_t)x2.x; A[5] = (half_t)x2.y;
            A[6] = (half_t)x3.x; A[7] = (half_t)x3.y;
            acc0 = __builtin_amdgcn_mfma_f32_16x16x32_f16(A, B[0][kh * 4 + kc], acc0, 0, 0, 0);
            acc1 = __builtin_amdgcn_mfma_f32_16x16x32_f16(A, B[1][kh * 4 + kc], acc1, 0, 0, 0);
        }
        if (kh == 0) asm volatile("s_waitcnt lgkmcnt(0)" ::: "memory");
    }

    // epilogue: dinv scale -> repack via xt (stride 33) -> coalesced half2 stores
    __syncthreads();
    float* sb = xw;
    #pragma unroll
    for (int r = 0; r < 4; ++r) {
        int rl = q * 4 + r;
        int grow = row0 + rl; if (grow >= NNODES) grow = NNODES - 1;
        float dv = dinv[grow];
        sb[rl * 33 + m]      = acc0[r] * dv;
        sb[rl * 33 + 16 + m] = acc1[r] * dv;
    }
    __syncthreads();
    int rl = (t >> 2) & 15;
    int w2 = t >> 6;
    int c0 = (t & 3) * 8;
    int grow = blockIdx.x * 64 + w2 * 16 + rl;
    if (grow < NNODES) {
        const float* sp = &xt[w2][rl * 33 + c0];
        __half2 h0 = __floats2half2_rn(sp[0], sp[1]);
        __half2 h1 = __floats2half2_rn(sp[2], sp[3]);
        __half2 h2 = __floats2half2_rn(sp[4], sp[5]);
        __half2 h3 = __floats2half2_rn(sp[6], sp[7]);
        __half2* gp = &g1[(size_t)grow * 16 + (c0 >> 1)];
        gp[0] = h0; gp[1] = h1; gp[2] = h2; gp[3] = h3;
    }
}

// ---------------- gather layer 1 (fp16 rows; fused relu + [Wm|Wv]) ----------------

__global__ __launch_bounds__(256) void k_gather_l1(
        const int* __restrict__ rowptr, const int* __restrict__ cnt,
        const int* __restrict__ csr,
        const float* __restrict__ dinv, const __half2* __restrict__ g,
        const float* __restrict__ b1, const float* __restrict__ Wm,
        const float* __restrict__ Wv, __half2* __restrict__ g2) {
    __shared__ float Wcat[F_HID * 32];
    __shared__ float hrow[16][F_HID + 2];
    int tx = threadIdx.x;
    for (int idx = tx; idx < F_HID * 32; idx += 256) {
        int k = idx >> 5, j = idx & 31;
        Wcat[idx] = (j < F_OUT) ? Wm[k * F_OUT + j] : Wv[k * F_OUT + (j - F_OUT)];
    }
    int f2 = tx & 15;
    int lr = tx >> 4;
    int node = blockIdx.x * 16 + lr;
    int start = rowptr[node], end = start + cnt[node];
    float2 acc = __half22float2(g[(size_t)node * 16 + f2]);   // self loop
    int j = start;
    for (; j + 4 <= end; j += 4) {
        int s0 = csr[j], s1 = csr[j + 1], s2 = csr[j + 2], s3 = csr[j + 3];
        float2 a0 = __half22float2(g[(size_t)s0 * 16 + f2]);
        float2 a1 = __half22float2(g[(size_t)s1 * 16 + f2]);
        float2 a2 = __half22float2(g[(size_t)s2 * 16 + f2]);
        float2 a3 = __half22float2(g[(size_t)s3 * 16 + f2]);
        acc.x += (a0.x + a1.x) + (a2.x + a3.x);
        acc.y += (a0.y + a1.y) + (a2.y + a3.y);
    }
    for (; j < end; ++j) {
        float2 a = __half22float2(g[(size_t)csr[j] * 16 + f2]);
        acc.x += a.x; acc.y += a.y;
    }
    float dv = dinv[node];
    float h0 = dv * acc.x + b1[2 * f2];
    float h1 = dv * acc.y + b1[2 * f2 + 1];
    hrow[lr][2 * f2]     = h0 > 0.f ? h0 : 0.f;
    hrow[lr][2 * f2 + 1] = h1 > 0.f ? h1 : 0.f;
    __syncthreads();
    float o0 = 0.f, o1 = 0.f;
    #pragma unroll
    for (int k = 0; k < F_HID; ++k) {
        float hv = hrow[lr][k];
        o0 = fmaf(hv, Wcat[k * 32 + 2 * f2], o0);
        o1 = fmaf(hv, Wcat[k * 32 + 2 * f2 + 1], o1);
    }
    g2[(size_t)node * 16 + f2] = __floats2half2_rn(o0 * dv, o1 * dv);
}

// ---------------- gather layer 2 (fp16 rows; fused bias + mu/sigma split) --------

__global__ __launch_bounds__(256) void k_gather_out(
        const int* __restrict__ rowptr, const int* __restrict__ cnt,
        const int* __restrict__ csr,
        const float* __restrict__ dinv, const __half2* __restrict__ g,
        const float* __restrict__ bm, const float* __restrict__ bv,
        float* __restrict__ out) {
    int tx = threadIdx.x;
    int f2 = tx & 15;
    int node = blockIdx.x * 16 + (tx >> 4);
    int start = rowptr[node], end = start + cnt[node];
    float2 acc = __half22float2(g[(size_t)node * 16 + f2]);   // self loop
    int j = start;
    for (; j + 4 <= end; j += 4) {
        int s0 = csr[j], s1 = csr[j + 1], s2 = csr[j + 2], s3 = csr[j + 3];
        float2 a0 = __half22float2(g[(size_t)s0 * 16 + f2]);
        float2 a1 = __half22float2(g[(size_t)s1 * 16 + f2]);
        float2 a2 = __half22float2(g[(size_t)s2 * 16 + f2]);
        float2 a3 = __half22float2(g[(size_t)s3 * 16 + f2]);
        acc.x += (a0.x + a1.x) + (a2.x + a3.x);
        acc.y += (a0.y + a1.y) + (a2.y + a3.y);
    }
    for (; j < end; ++j) {
        float2 a = __half22float2(g[(size_t)csr[j] * 16 + f2]);
        acc.x += a.x; acc.y += a.y;
    }
    float dv = dinv[node];
    int f = 2 * f2;
    if (f < F_OUT) {
        float2 o = { dv * acc.x + bm[f], dv * acc.y + bm[f + 1] };
        *(float2*)&out[(size_t)node * F_OUT + f] = o;
    } else {
        float2 o = { dv * acc.x + bv[f - F_OUT], dv * acc.y + bv[f - F_OUT + 1] };
        *(float2*)&out[(size_t)NNODES * F_OUT + (size_t)node * F_OUT + (f - F_OUT)] = o;
    }
}

// ---------------- launch ----------------

extern "C" void kernel_launch(void* const* d_in, const int* in_sizes, int n_in,
                              void* d_out, int out_size, void* d_ws, size_t ws_size,
                              hipStream_t stream) {
    const float* x   = (const float*)d_in[0];
    const int*   ei  = (const int*)  d_in[1];
    const float* W1  = (const float*)d_in[2];
    const float* b1  = (const float*)d_in[3];
    const float* Wm  = (const float*)d_in[4];
    const float* bm  = (const float*)d_in[5];
    const float* Wv  = (const float*)d_in[6];
    const float* bv  = (const float*)d_in[7];
    float* out = (float*)d_out;

    const int* src = ei;
    const int* dst = ei + NEDGES;

    // workspace layout (4B units), ~40 MB:
    char* ws = (char*)d_ws;
    float*        dinv   = (float*)ws;        ws += 100352 * 4;
    int*          bcur   = (int*)ws;          ws += 256 * 4;
    int*          rowptr = (int*)ws;          ws += 100352 * 4;
    int*          cnt    = (int*)ws;          ws += 100352 * 4;
    int*          csr    = (int*)ws;          ws += (size_t)NB * CAP * 4;
    unsigned int* rec    = (unsigned int*)ws; ws += (size_t)NB * CAP * 4;
    __half2*      g2     = (__half2*)ws;

    __half2* g1 = (__half2*)rec;   // rec dead after k_phaseB

    // CSR build
    k_init  <<<1, 256, 0, stream>>>(bcur);
    k_phaseA<<<NCHUNK, 1024, 0, stream>>>(src, dst, bcur, rec);
    k_phaseB<<<NB, 1024, 0, stream>>>(rec, bcur, rowptr, cnt, dinv, csr);

    // layer 1 GEMM (MFMA, async LDS staging)
    k_gemm1<<<GRID1, 256, 0, stream>>>(x, W1, dinv, g1);

    // gather 1 + relu + second transform (mu|sigma fused)
    k_gather_l1<<<NNODES / 16, 256, 0, stream>>>(rowptr, cnt, csr, dinv, g1, b1, Wm, Wv, g2);

    // gather 2 + bias + split to out
    k_gather_out<<<NNODES / 16, 256, 0, stream>>>(rowptr, cnt, csr, dinv, g2, bm, bv, out);
}

// Round 8
// 320.658 us; speedup vs baseline: 5.3745x; 1.0525x over previous
//
#include <hip/hip_runtime.h>
#include <hip/hip_fp16.h>

#define NNODES 100000
#define NEDGES 3200000
#define F_IN   256
#define F_HID  32
#define F_OUT  16

#define NB   196      // ceil(100000/512) buckets of 512 nodes
#define NPB  512      // nodes per bucket
#define CAP  20480    // fixed capacity per bucket region (mean 16327, +32 sigma); = 20*1024
#define NCHUNK 256    // phase-A blocks: keeps reservations ~64 records = dense writes
#define CHUNK  12500  // edges per phase-A block
#define RPT_B  20     // phaseB records/thread (CAP/1024)
#define RPT_A  13     // phaseA dst regs/thread (ceil(CHUNK/1024))

#define GRID1 ((NNODES + 63) / 64)   // 1563 blocks, 64 rows/block (16/wave)

typedef _Float16 half_t;
typedef half_t half8 __attribute__((ext_vector_type(8)));
typedef float f32x4 __attribute__((ext_vector_type(4)));

// ---------------- CSR build (fixed-capacity buckets) ----------------
// Verified lessons (r1/r3/r4 counters):
//  - scattered 4B HBM writes cost a full 64B line each (r3 k_place: 196MB
//    WRITE for a 12.8MB payload) -> only block-local contiguous reservations
//    write densely (this scheme: ~15MB).
//  - finer reservations (r1: 1024 blocks) fragment lines -> 4x write amp.
//    So NCHUNK stays 256; occupancy comes from 1024 threads/block.
//  - gather-side kernels must run thousands of blocks; 196-block LDS
//    accumulation (r4) starves the GPU and thrashes per-XCD 4MB L2.

__global__ void k_init(int* __restrict__ bcur) {
    if (threadIdx.x < NB) bcur[threadIdx.x] = threadIdx.x * CAP;
}

// Phase A: partition edges into bucket regions as packed records (src<<9)|dstLocal.
// dst chunk is register-cached across the hist and placement passes (13 VGPRs,
// fully unrolled -> no scratch) so dst is read from memory exactly once.
__global__ __launch_bounds__(1024) void k_phaseA(
        const int* __restrict__ src, const int* __restrict__ dst,
        int* __restrict__ bcur, unsigned int* __restrict__ rec) {
    __shared__ int lh[NB];
    __shared__ int lcur[NB];
    int t = threadIdx.x;
    int e0 = blockIdx.x * CHUNK;
    if (t < NB) lh[t] = 0;

    int dcache[RPT_A];
    #pragma unroll
    for (int k = 0; k < RPT_A; ++k) {
        int i = t + k * 1024;
        dcache[k] = (i < CHUNK) ? dst[e0 + i] : -1;
    }
    __syncthreads();
    #pragma unroll
    for (int k = 0; k < RPT_A; ++k)
        if (dcache[k] >= 0) atomicAdd(&lh[dcache[k] >> 9], 1);
    __syncthreads();
    if (t < NB) lcur[t] = lh[t] ? atomicAdd(&bcur[t], lh[t]) : 0;
    __syncthreads();
    #pragma unroll
    for (int k = 0; k < RPT_A; ++k) {
        int i = t + k * 1024;
        if (dcache[k] >= 0) {
            int s = src[e0 + i];
            int d = dcache[k];
            int b = d >> 9;
            int pos = atomicAdd(&lcur[b], 1);
            rec[pos] = ((unsigned)s << 9) | (unsigned)(d & 511);
        }
    }
}

// Phase B (single-pass): load the bucket's records into registers (20/thread,
// coalesced stream, fully unrolled), then hist -> shuffle scan -> rowptr/cnt/
// dinv -> placement, all from registers. rec is read from memory exactly once.
__global__ __launch_bounds__(1024) void k_phaseB(
        const unsigned int* __restrict__ rec, const int* __restrict__ bcur,
        int* __restrict__ rowptr, int* __restrict__ cnt,
        float* __restrict__ dinv, int* __restrict__ csr) {
    __shared__ int lh[NPB];
    __shared__ int lsc[NPB];
    __shared__ int wsum[16];
    int t = threadIdx.x, b = blockIdx.x;
    int lo = b * CAP;
    int nrec = bcur[b] - lo;
    if (t < NPB) lh[t] = 0;

    unsigned rcache[RPT_B];
    #pragma unroll
    for (int k = 0; k < RPT_B; ++k) {
        int i = t + k * 1024;
        rcache[k] = (i < nrec) ? rec[lo + i] : 0xFFFFFFFFu;  // recs < 2^26: safe sentinel
    }
    __syncthreads();
    #pragma unroll
    for (int k = 0; k < RPT_B; ++k)
        if (rcache[k] != 0xFFFFFFFFu) atomicAdd(&lh[rcache[k] & 511], 1);
    __syncthreads();

    int lane = t & 63, w = t >> 6;
    int my = (t < NPB) ? lh[t] : 0;
    int v = my;
    #pragma unroll
    for (int d = 1; d < 64; d <<= 1) {
        int tmp = __shfl_up(v, d, 64);
        if (lane >= d) v += tmp;
    }
    if (lane == 63) wsum[w] = v;
    __syncthreads();
    if (w == 0) {
        int s = (lane < 16) ? wsum[lane] : 0;
        #pragma unroll
        for (int d = 1; d < 16; d <<= 1) {
            int tmp = __shfl_up(s, d, 64);
            if (lane >= d) s += tmp;
        }
        if (lane < 16) wsum[lane] = s;
    }
    __syncthreads();
    int ex = v + (w > 0 ? wsum[w - 1] : 0) - my;   // exclusive
    int node = b * NPB + t;
    if (t < NPB) {
        lsc[t] = ex;
        if (node < NNODES) {
            rowptr[node] = lo + ex;
            cnt[node] = my;
            dinv[node] = rsqrtf((float)my + 1.0f);
        }
    }
    __syncthreads();
    #pragma unroll
    for (int k = 0; k < RPT_B; ++k)
        if (rcache[k] != 0xFFFFFFFFu) {
            int dl = rcache[k] & 511;
            int p = atomicAdd(&lsc[dl], 1);
            csr[lo + p] = (int)(rcache[k] >> 9);
        }
}

// ---------------- layer-1 GEMM via MFMA, A direct global->register ----------------
// Wt: W1 transposed to fp16 in LDS once -> B frags via 16 ds_read_b128 (one-time).
// A: each lane's fragment is 8 CONTIGUOUS floats of one x row (32B aligned), so
// load global->register directly (2x float4 per k-block). No LDS staging for A:
// deletes 64 width-4 global_load_lds issues, two vmcnt(0) drains, 32 ds_reads
// and the repack per tile. LDS drops 50KB -> 25KB (more blocks/CU -> TLP hides
// the raw global latency). Per-instruction coalescing: 64 lanes touch 16 rows
// x 128B fully-consumed segments; each row still read exactly once.

__global__ __launch_bounds__(256) void k_gemm1(
        const float* __restrict__ x, const float* __restrict__ W1,
        const float* __restrict__ dinv, __half2* __restrict__ g1) {
    __shared__ half_t Wt[32 * 264];       // [f][k] fp16, 16.9 KB
    __shared__ float sb4[4][16 * 33];     // per-wave epilogue repack, 8.4 KB
    int t = threadIdx.x;
    int wave = t >> 6, lane = t & 63;
    int m = lane & 15, q = lane >> 4;
    int row0 = blockIdx.x * 64 + wave * 16;

    for (int i = t; i < F_IN * F_HID; i += 256) {
        int k = i >> 5, f = i & 31;
        Wt[f * 264 + k] = (half_t)W1[i];
    }
    __syncthreads();

    half8 B[2][8];
    #pragma unroll
    for (int ft = 0; ft < 2; ++ft)
        #pragma unroll
        for (int kc = 0; kc < 8; ++kc)
            B[ft][kc] = *(const half8*)&Wt[(ft * 16 + m) * 264 + kc * 32 + q * 8];

    int grow_a = row0 + m; if (grow_a >= NNODES) grow_a = NNODES - 1;
    const float* rowp = &x[(size_t)grow_a * F_IN + q * 8];

    f32x4 acc0 = {0.f, 0.f, 0.f, 0.f};
    f32x4 acc1 = {0.f, 0.f, 0.f, 0.f};
    #pragma unroll
    for (int kb = 0; kb < 8; ++kb) {      // 8 k-blocks of 32
        const float* sp = rowp + kb * 32;
        float4 xa = *(const float4*)sp;
        float4 xb = *(const float4*)(sp + 4);
        half8 A;
        A[0] = (half_t)xa.x; A[1] = (half_t)xa.y;
        A[2] = (half_t)xa.z; A[3] = (half_t)xa.w;
        A[4] = (half_t)xb.x; A[5] = (half_t)xb.y;
        A[6] = (half_t)xb.z; A[7] = (half_t)xb.w;
        acc0 = __builtin_amdgcn_mfma_f32_16x16x32_f16(A, B[0][kb], acc0, 0, 0, 0);
        acc1 = __builtin_amdgcn_mfma_f32_16x16x32_f16(A, B[1][kb], acc1, 0, 0, 0);
    }

    // epilogue: dinv scale -> repack via sb4 (stride 33) -> coalesced half2 stores
    float* sb = sb4[wave];
    #pragma unroll
    for (int r = 0; r < 4; ++r) {
        int rl = q * 4 + r;
        int grow = row0 + rl; if (grow >= NNODES) grow = NNODES - 1;
        float dv = dinv[grow];
        sb[rl * 33 + m]      = acc0[r] * dv;
        sb[rl * 33 + 16 + m] = acc1[r] * dv;
    }
    __syncthreads();
    int rl = (t >> 2) & 15;
    int w2 = t >> 6;
    int c0 = (t & 3) * 8;
    int grow = blockIdx.x * 64 + w2 * 16 + rl;
    if (grow < NNODES) {
        const float* sp = &sb4[w2][rl * 33 + c0];
        __half2 h0 = __floats2half2_rn(sp[0], sp[1]);
        __half2 h1 = __floats2half2_rn(sp[2], sp[3]);
        __half2 h2 = __floats2half2_rn(sp[4], sp[5]);
        __half2 h3 = __floats2half2_rn(sp[6], sp[7]);
        __half2* gp = &g1[(size_t)grow * 16 + (c0 >> 1)];
        gp[0] = h0; gp[1] = h1; gp[2] = h2; gp[3] = h3;
    }
}

// ---------------- gather layer 1 (fp16 rows; fused relu + [Wm|Wv]) ----------------
// Gather is latency-bound (6.4MB row table > 4MB per-XCD L2 -> L2-miss/L3-hit
// chains); unroll 8 keeps 8 independent row reads in flight per thread.

__global__ __launch_bounds__(256) void k_gather_l1(
        const int* __restrict__ rowptr, const int* __restrict__ cnt,
        const int* __restrict__ csr,
        const float* __restrict__ dinv, const __half2* __restrict__ g,
        const float* __restrict__ b1, const float* __restrict__ Wm,
        const float* __restrict__ Wv, __half2* __restrict__ g2) {
    __shared__ float Wcat[F_HID * 32];
    __shared__ float hrow[16][F_HID + 2];
    int tx = threadIdx.x;
    for (int idx = tx; idx < F_HID * 32; idx += 256) {
        int k = idx >> 5, j = idx & 31;
        Wcat[idx] = (j < F_OUT) ? Wm[k * F_OUT + j] : Wv[k * F_OUT + (j - F_OUT)];
    }
    int f2 = tx & 15;
    int lr = tx >> 4;
    int node = blockIdx.x * 16 + lr;
    int start = rowptr[node], end = start + cnt[node];
    float2 acc = __half22float2(g[(size_t)node * 16 + f2]);   // self loop
    int j = start;
    for (; j + 8 <= end; j += 8) {
        int s[8];
        #pragma unroll
        for (int u = 0; u < 8; ++u) s[u] = csr[j + u];
        float2 a[8];
        #pragma unroll
        for (int u = 0; u < 8; ++u) a[u] = __half22float2(g[(size_t)s[u] * 16 + f2]);
        float sx = 0.f, sy = 0.f;
        #pragma unroll
        for (int u = 0; u < 8; ++u) { sx += a[u].x; sy += a[u].y; }
        acc.x += sx; acc.y += sy;
    }
    for (; j + 4 <= end; j += 4) {
        int s0 = csr[j], s1 = csr[j + 1], s2 = csr[j + 2], s3 = csr[j + 3];
        float2 a0 = __half22float2(g[(size_t)s0 * 16 + f2]);
        float2 a1 = __half22float2(g[(size_t)s1 * 16 + f2]);
        float2 a2 = __half22float2(g[(size_t)s2 * 16 + f2]);
        float2 a3 = __half22float2(g[(size_t)s3 * 16 + f2]);
        acc.x += (a0.x + a1.x) + (a2.x + a3.x);
        acc.y += (a0.y + a1.y) + (a2.y + a3.y);
    }
    for (; j < end; ++j) {
        float2 a = __half22float2(g[(size_t)csr[j] * 16 + f2]);
        acc.x += a.x; acc.y += a.y;
    }
    float dv = dinv[node];
    float h0 = dv * acc.x + b1[2 * f2];
    float h1 = dv * acc.y + b1[2 * f2 + 1];
    hrow[lr][2 * f2]     = h0 > 0.f ? h0 : 0.f;
    hrow[lr][2 * f2 + 1] = h1 > 0.f ? h1 : 0.f;
    __syncthreads();
    float o0 = 0.f, o1 = 0.f;
    #pragma unroll
    for (int k = 0; k < F_HID; ++k) {
        float hv = hrow[lr][k];
        o0 = fmaf(hv, Wcat[k * 32 + 2 * f2], o0);
        o1 = fmaf(hv, Wcat[k * 32 + 2 * f2 + 1], o1);
    }
    g2[(size_t)node * 16 + f2] = __floats2half2_rn(o0 * dv, o1 * dv);
}

// ---------------- gather layer 2 (fp16 rows; fused bias + mu/sigma split) --------

__global__ __launch_bounds__(256) void k_gather_out(
        const int* __restrict__ rowptr, const int* __restrict__ cnt,
        const int* __restrict__ csr,
        const float* __restrict__ dinv, const __half2* __restrict__ g,
        const float* __restrict__ bm, const float* __restrict__ bv,
        float* __restrict__ out) {
    int tx = threadIdx.x;
    int f2 = tx & 15;
    int node = blockIdx.x * 16 + (tx >> 4);
    int start = rowptr[node], end = start + cnt[node];
    float2 acc = __half22float2(g[(size_t)node * 16 + f2]);   // self loop
    int j = start;
    for (; j + 8 <= end; j += 8) {
        int s[8];
        #pragma unroll
        for (int u = 0; u < 8; ++u) s[u] = csr[j + u];
        float2 a[8];
        #pragma unroll
        for (int u = 0; u < 8; ++u) a[u] = __half22float2(g[(size_t)s[u] * 16 + f2]);
        float sx = 0.f, sy = 0.f;
        #pragma unroll
        for (int u = 0; u < 8; ++u) { sx += a[u].x; sy += a[u].y; }
        acc.x += sx; acc.y += sy;
    }
    for (; j + 4 <= end; j += 4) {
        int s0 = csr[j], s1 = csr[j + 1], s2 = csr[j + 2], s3 = csr[j + 3];
        float2 a0 = __half22float2(g[(size_t)s0 * 16 + f2]);
        float2 a1 = __half22float2(g[(size_t)s1 * 16 + f2]);
        float2 a2 = __half22float2(g[(size_t)s2 * 16 + f2]);
        float2 a3 = __half22float2(g[(size_t)s3 * 16 + f2]);
        acc.x += (a0.x + a1.x) + (a2.x + a3.x);
        acc.y += (a0.y + a1.y) + (a2.y + a3.y);
    }
    for (; j < end; ++j) {
        float2 a = __half22float2(g[(size_t)csr[j] * 16 + f2]);
        acc.x += a.x; acc.y += a.y;
    }
    float dv = dinv[node];
    int f = 2 * f2;
    if (f < F_OUT) {
        float2 o = { dv * acc.x + bm[f], dv * acc.y + bm[f + 1] };
        *(float2*)&out[(size_t)node * F_OUT + f] = o;
    } else {
        float2 o = { dv * acc.x + bv[f - F_OUT], dv * acc.y + bv[f - F_OUT + 1] };
        *(float2*)&out[(size_t)NNODES * F_OUT + (size_t)node * F_OUT + (f - F_OUT)] = o;
    }
}

// ---------------- launch ----------------

extern "C" void kernel_launch(void* const* d_in, const int* in_sizes, int n_in,
                              void* d_out, int out_size, void* d_ws, size_t ws_size,
                              hipStream_t stream) {
    const float* x   = (const float*)d_in[0];
    const int*   ei  = (const int*)  d_in[1];
    const float* W1  = (const float*)d_in[2];
    const float* b1  = (const float*)d_in[3];
    const float* Wm  = (const float*)d_in[4];
    const float* bm  = (const float*)d_in[5];
    const float* Wv  = (const float*)d_in[6];
    const float* bv  = (const float*)d_in[7];
    float* out = (float*)d_out;

    const int* src = ei;
    const int* dst = ei + NEDGES;

    // workspace layout (4B units), ~40 MB:
    char* ws = (char*)d_ws;
    float*        dinv   = (float*)ws;        ws += 100352 * 4;
    int*          bcur   = (int*)ws;          ws += 256 * 4;
    int*          rowptr = (int*)ws;          ws += 100352 * 4;
    int*          cnt    = (int*)ws;          ws += 100352 * 4;
    int*          csr    = (int*)ws;          ws += (size_t)NB * CAP * 4;
    unsigned int* rec    = (unsigned int*)ws; ws += (size_t)NB * CAP * 4;
    __half2*      g2     = (__half2*)ws;

    __half2* g1 = (__half2*)rec;   // rec dead after k_phaseB

    // CSR build
    k_init  <<<1, 256, 0, stream>>>(bcur);
    k_phaseA<<<NCHUNK, 1024, 0, stream>>>(src, dst, bcur, rec);
    k_phaseB<<<NB, 1024, 0, stream>>>(rec, bcur, rowptr, cnt, dinv, csr);

    // layer 1 GEMM (MFMA, A direct global->register)
    k_gemm1<<<GRID1, 256, 0, stream>>>(x, W1, dinv, g1);

    // gather 1 + relu + second transform (mu|sigma fused)
    k_gather_l1<<<NNODES / 16, 256, 0, stream>>>(rowptr, cnt, csr, dinv, g1, b1, Wm, Wv, g2);

    // gather 2 + bias + split to out
    k_gather_out<<<NNODES / 16, 256, 0, stream>>>(rowptr, cnt, csr, dinv, g2, bm, bv, out);
}